// Round 2
// baseline (327.325 us; speedup 1.0000x reference)
//
#include <hip/hip_runtime.h>

#define THREADS 256
#define GRID 2048
#define PT 8   // float4 per array per thread: 16M/4 / (2048*256) = exactly 8

// Fused kernel: per-block partial sums + deterministic last-block finalize.
// percentiles is a uniform grid (linspace), so nearest-bin is analytic:
//   idx = clamp(rint((t - p0) * (P-1)/(pL - p0)), 0, P-1)
//
// MLP forcing: each thread's ENTIRE workload (8 float4 from each array) is
// issued as 16 back-to-back global_load_dwordx4 before any consumption;
// __builtin_amdgcn_sched_barrier(0) pins the schedule so the compiler
// cannot interleave/serialize. VGPR ~80 expected (proof the loads are live).
__global__ __launch_bounds__(THREADS) void loss_kernel(
    const float* __restrict__ outputs,
    const float* __restrict__ targets,
    const float* __restrict__ per,
    float* __restrict__ partials,
    unsigned int* __restrict__ cnt,
    float* __restrict__ out,
    int n, int P, float inv_maxbin, double inv_n) {

    // Uniform-grid parameters — wave-uniform, L2-cached.
    const float p0 = per[0];
    const float pL = per[P - 1];
    const float inv_h = (float)(P - 1) / (pL - p0);
    const float kmax = (float)(P - 1);

    const int n4 = n >> 2;
    const float4* __restrict__ o4 = (const float4*)outputs;
    const float4* __restrict__ t4 = (const float4*)targets;

    const int tid = blockIdx.x * THREADS + threadIdx.x;
    const int S = GRID * THREADS;   // compile-time constant stride

    float acc = 0.0f;
    int i = tid;

    // Main path: issue all PT*2 loads, fence, then compute.
    for (; i + (PT - 1) * S < n4; i += PT * S) {   // executes exactly once for N=16M
        float4 o[PT], t[PT];
        #pragma unroll
        for (int u = 0; u < PT; ++u) o[u] = o4[i + u * S];
        #pragma unroll
        for (int u = 0; u < PT; ++u) t[u] = t4[i + u * S];
        __builtin_amdgcn_sched_barrier(0);   // nothing crosses: 16 loads stay issued
        #pragma unroll
        for (int u = 0; u < PT; ++u) {
            #pragma unroll
            for (int c = 0; c < 4; ++c) {
                float tv = (c == 0) ? t[u].x : (c == 1) ? t[u].y : (c == 2) ? t[u].z : t[u].w;
                float ov = (c == 0) ? o[u].x : (c == 1) ? o[u].y : (c == 2) ? o[u].z : o[u].w;
                float k = rintf((tv - p0) * inv_h);
                k = fminf(fmaxf(k, 0.0f), kmax);        // clamp to [0, P-1]
                float f = (k + 1.0f) * inv_maxbin;      // factors = (idx+1)/P
                float e = tv - ov;                      // targets - outputs
                acc += fmaxf((f - 1.0f) * e, f * e);    // pinball loss
            }
        }
    }

    // Leftover float4 (generality; empty for N = 16M).
    for (; i < n4; i += S) {
        float4 o = o4[i];
        float4 t = t4[i];
        #pragma unroll
        for (int c = 0; c < 4; ++c) {
            float tv = (c == 0) ? t.x : (c == 1) ? t.y : (c == 2) ? t.z : t.w;
            float ov = (c == 0) ? o.x : (c == 1) ? o.y : (c == 2) ? o.z : o.w;
            float k = rintf((tv - p0) * inv_h);
            k = fminf(fmaxf(k, 0.0f), kmax);
            float f = (k + 1.0f) * inv_maxbin;
            float e = tv - ov;
            acc += fmaxf((f - 1.0f) * e, f * e);
        }
    }

    // Scalar tail (n % 4 != 0) — no-op for N = 16M, kept for safety.
    const int tail = n & 3;
    if (tail && blockIdx.x == 0 && threadIdx.x < tail) {
        int j = (n4 << 2) + threadIdx.x;
        float tv = targets[j];
        float ov = outputs[j];
        float k = rintf((tv - p0) * inv_h);
        k = fminf(fmaxf(k, 0.0f), kmax);
        float f = (k + 1.0f) * inv_maxbin;
        float e = tv - ov;
        acc += fmaxf((f - 1.0f) * e, f * e);
    }

    // Wave (64-lane) shuffle reduction.
    #pragma unroll
    for (int off = 32; off > 0; off >>= 1)
        acc += __shfl_down(acc, off, 64);

    __shared__ float lds[THREADS / 64];
    __shared__ int is_last;
    const int lane = threadIdx.x & 63;
    const int wave = threadIdx.x >> 6;
    if (lane == 0) lds[wave] = acc;
    __syncthreads();

    if (threadIdx.x == 0) {
        float s = 0.0f;
        #pragma unroll
        for (int w = 0; w < THREADS / 64; ++w) s += lds[w];
        // Device-scope release of this block's partial, then arrival count.
        __hip_atomic_store(&partials[blockIdx.x], s, __ATOMIC_RELEASE,
                           __HIP_MEMORY_SCOPE_AGENT);
        unsigned int old = __hip_atomic_fetch_add(cnt, 1u, __ATOMIC_ACQ_REL,
                                                  __HIP_MEMORY_SCOPE_AGENT);
        is_last = (old == (unsigned int)(gridDim.x - 1)) ? 1 : 0;
    }
    __syncthreads();

    // Deterministic last-block finalize (sum order is fixed: strided by thread,
    // then wave-shuffle tree, then 4 LDS slots — same every run).
    if (is_last) {
        double a = 0.0;
        for (int j = threadIdx.x; j < (int)gridDim.x; j += THREADS)
            a += (double)__hip_atomic_load(&partials[j], __ATOMIC_RELAXED,
                                           __HIP_MEMORY_SCOPE_AGENT);
        #pragma unroll
        for (int off = 32; off > 0; off >>= 1)
            a += __shfl_down(a, off, 64);

        __shared__ double dlds[THREADS / 64];
        if (lane == 0) dlds[wave] = a;
        __syncthreads();
        if (threadIdx.x == 0) {
            double sd = 0.0;
            #pragma unroll
            for (int w = 0; w < THREADS / 64; ++w) sd += dlds[w];
            out[0] = (float)(sd * inv_n);
        }
    }
}

extern "C" void kernel_launch(void* const* d_in, const int* in_sizes, int n_in,
                              void* d_out, int out_size, void* d_ws, size_t ws_size,
                              hipStream_t stream) {
    const float* outputs     = (const float*)d_in[0];
    const float* targets     = (const float*)d_in[1];
    const float* percentiles = (const float*)d_in[2];
    float* out = (float*)d_out;

    const int n = in_sizes[0];
    const int P = in_sizes[2];

    // Workspace layout: GRID floats (partials) + 1 uint (arrival counter).
    float* partials = (float*)d_ws;
    unsigned int* cnt = (unsigned int*)((char*)d_ws + GRID * sizeof(float));

    // Counter must be 0 at every replay (d_ws may be re-poisoned between
    // iterations). 4-byte async memset is graph-capturable and cheap.
    hipMemsetAsync(cnt, 0, sizeof(unsigned int), stream);

    loss_kernel<<<GRID, THREADS, 0, stream>>>(
        outputs, targets, percentiles, partials, cnt, out,
        n, P, 1.0f / (float)P, 1.0 / (double)n);
}

// Round 3
// 157.323 us; speedup vs baseline: 2.0806x; 2.0806x over previous
//
#include <hip/hip_runtime.h>

#define THREADS 256
#define GRID 2048
#define PT 8   // float4 per array per thread: 16M/4 / (2048*256) = exactly 8

// Kernel 1: per-block partial sums of the risk-aware MAE loss.
// percentiles is a uniform grid (linspace), so nearest-bin is analytic:
//   idx = clamp(rint((t - p0) * (P-1)/(pL - p0)), 0, P-1)
//
// Main loop identical to Round 2 (PT=8 batch, sched_barrier fence) to isolate
// the Round-2 regression to the fused atomic tail (reverted here).
__global__ __launch_bounds__(THREADS) void loss_partial_kernel(
    const float* __restrict__ outputs,
    const float* __restrict__ targets,
    const float* __restrict__ per,
    float* __restrict__ partials,
    int n, int P, float inv_maxbin) {

    // Uniform-grid parameters — wave-uniform, L2-cached.
    const float p0 = per[0];
    const float pL = per[P - 1];
    const float inv_h = (float)(P - 1) / (pL - p0);
    const float kmax = (float)(P - 1);

    const int n4 = n >> 2;
    const float4* __restrict__ o4 = (const float4*)outputs;
    const float4* __restrict__ t4 = (const float4*)targets;

    const int tid = blockIdx.x * THREADS + threadIdx.x;
    const int S = GRID * THREADS;   // compile-time constant stride

    float acc = 0.0f;
    int i = tid;

    // Main path: issue all PT*2 loads, fence, then compute.
    for (; i + (PT - 1) * S < n4; i += PT * S) {   // executes exactly once for N=16M
        float4 o[PT], t[PT];
        #pragma unroll
        for (int u = 0; u < PT; ++u) o[u] = o4[i + u * S];
        #pragma unroll
        for (int u = 0; u < PT; ++u) t[u] = t4[i + u * S];
        __builtin_amdgcn_sched_barrier(0);   // loads stay issued ahead of compute
        #pragma unroll
        for (int u = 0; u < PT; ++u) {
            #pragma unroll
            for (int c = 0; c < 4; ++c) {
                float tv = (c == 0) ? t[u].x : (c == 1) ? t[u].y : (c == 2) ? t[u].z : t[u].w;
                float ov = (c == 0) ? o[u].x : (c == 1) ? o[u].y : (c == 2) ? o[u].z : o[u].w;
                float k = rintf((tv - p0) * inv_h);
                k = fminf(fmaxf(k, 0.0f), kmax);        // clamp to [0, P-1]
                float f = (k + 1.0f) * inv_maxbin;      // factors = (idx+1)/P
                float e = tv - ov;                      // targets - outputs
                acc += fmaxf((f - 1.0f) * e, f * e);    // pinball loss
            }
        }
    }

    // Leftover float4 (generality; empty for N = 16M).
    for (; i < n4; i += S) {
        float4 o = o4[i];
        float4 t = t4[i];
        #pragma unroll
        for (int c = 0; c < 4; ++c) {
            float tv = (c == 0) ? t.x : (c == 1) ? t.y : (c == 2) ? t.z : t.w;
            float ov = (c == 0) ? o.x : (c == 1) ? o.y : (c == 2) ? o.z : o.w;
            float k = rintf((tv - p0) * inv_h);
            k = fminf(fmaxf(k, 0.0f), kmax);
            float f = (k + 1.0f) * inv_maxbin;
            float e = tv - ov;
            acc += fmaxf((f - 1.0f) * e, f * e);
        }
    }

    // Scalar tail (n % 4 != 0) — no-op for N = 16M, kept for safety.
    const int tail = n & 3;
    if (tail && blockIdx.x == 0 && threadIdx.x < tail) {
        int j = (n4 << 2) + threadIdx.x;
        float tv = targets[j];
        float ov = outputs[j];
        float k = rintf((tv - p0) * inv_h);
        k = fminf(fmaxf(k, 0.0f), kmax);
        float f = (k + 1.0f) * inv_maxbin;
        float e = tv - ov;
        acc += fmaxf((f - 1.0f) * e, f * e);
    }

    // Wave (64-lane) shuffle reduction.
    #pragma unroll
    for (int off = 32; off > 0; off >>= 1)
        acc += __shfl_down(acc, off, 64);

    __shared__ float lds[THREADS / 64];
    const int lane = threadIdx.x & 63;
    const int wave = threadIdx.x >> 6;
    if (lane == 0) lds[wave] = acc;
    __syncthreads();
    if (threadIdx.x == 0) {
        float s = 0.0f;
        #pragma unroll
        for (int w = 0; w < THREADS / 64; ++w) s += lds[w];
        partials[blockIdx.x] = s;
    }
}

// Kernel 2: reduce block partials in double, write mean as f32.
__global__ __launch_bounds__(THREADS) void finalize_kernel(
    const float* __restrict__ partials, int nblocks,
    float* __restrict__ out, double inv_n) {

    double acc = 0.0;
    for (int i = threadIdx.x; i < nblocks; i += blockDim.x)
        acc += (double)partials[i];

    #pragma unroll
    for (int off = 32; off > 0; off >>= 1)
        acc += __shfl_down(acc, off, 64);

    __shared__ double lds[THREADS / 64];
    const int lane = threadIdx.x & 63;
    const int wave = threadIdx.x >> 6;
    if (lane == 0) lds[wave] = acc;
    __syncthreads();
    if (threadIdx.x == 0) {
        double s = 0.0;
        #pragma unroll
        for (int w = 0; w < THREADS / 64; ++w) s += lds[w];
        out[0] = (float)(s * inv_n);
    }
}

extern "C" void kernel_launch(void* const* d_in, const int* in_sizes, int n_in,
                              void* d_out, int out_size, void* d_ws, size_t ws_size,
                              hipStream_t stream) {
    const float* outputs     = (const float*)d_in[0];
    const float* targets     = (const float*)d_in[1];
    const float* percentiles = (const float*)d_in[2];
    float* out = (float*)d_out;

    const int n = in_sizes[0];
    const int P = in_sizes[2];

    float* partials = (float*)d_ws;   // GRID floats, fully written before read

    loss_partial_kernel<<<GRID, THREADS, 0, stream>>>(
        outputs, targets, percentiles, partials, n, P, 1.0f / (float)P);

    finalize_kernel<<<1, THREADS, 0, stream>>>(
        partials, GRID, out, 1.0 / (double)n);
}

// Round 4
// 153.098 us; speedup vs baseline: 2.1380x; 1.0276x over previous
//
#include <hip/hip_runtime.h>

#define THREADS 256
#define GRID 2048
#define PT 8   // float4 per array per thread: 16M/4 / (2048*256) = exactly 8

typedef __attribute__((address_space(1))) const void GASV;  // global
typedef __attribute__((address_space(3))) void LASV;        // LDS

// Kernel 1: per-block partial sums of the risk-aware MAE loss.
// percentiles is a uniform grid (linspace), so nearest-bin is analytic:
//   idx = clamp(rint((t - p0) * (P-1)/(pL - p0)), 0, P-1)
//
// Dual-path experiment: targets stream through the LDS-DMA path
// (global_load_lds, 16B/lane) while outputs stream through the normal
// vector-load path — both concurrently in flight. If the two paths have
// independent per-CU miss tracking, read BW can exceed the ~3.15 TB/s
// single-path cap observed in R0/R1/R3.
__global__ __launch_bounds__(THREADS) void loss_partial_kernel(
    const float* __restrict__ outputs,
    const float* __restrict__ targets,
    const float* __restrict__ per,
    float* __restrict__ partials,
    int n, int P, float inv_maxbin) {

    // Uniform-grid parameters — wave-uniform, L2-cached.
    const float p0 = per[0];
    const float pL = per[P - 1];
    const float inv_h = (float)(P - 1) / (pL - p0);
    const float kmax = (float)(P - 1);

    const int n4 = n >> 2;
    const float4* __restrict__ o4 = (const float4*)outputs;
    const float4* __restrict__ t4 = (const float4*)targets;

    const int tid = threadIdx.x;
    const int S = GRID * THREADS;   // compile-time constant stride

    __shared__ float4 tstage[PT][THREADS];   // 32 KB — 5 blocks/CU (LDS-limited)

    float acc = 0.0f;

    if (n4 == PT * S) {
        // Exact-shape fast path (holds for N = 16M).
        const int base = blockIdx.x * THREADS + tid;
        const int wave = tid >> 6;

        // 1) Issue 8 LDS-DMA loads of targets. Global src addr is per-lane;
        //    LDS dest is wave-uniform base + lane*16 (linear, matches read).
        #pragma unroll
        for (int u = 0; u < PT; ++u) {
            __builtin_amdgcn_global_load_lds(
                (GASV*)&t4[u * S + base],
                (LASV*)&tstage[u][wave * 64],
                16, 0, 0);
        }

        // 2) Issue 8 vector loads of outputs into VGPRs (independent path).
        float4 o[PT];
        #pragma unroll
        for (int u = 0; u < PT; ++u) o[u] = o4[u * S + base];

        // 3) One barrier: drains vmcnt (both paths) + orders LDS writes.
        __syncthreads();

        // 4) Combine. LDS reads are lane-contiguous 16B — conflict-free.
        #pragma unroll
        for (int u = 0; u < PT; ++u) {
            float4 t = tstage[u][tid];
            #pragma unroll
            for (int c = 0; c < 4; ++c) {
                float tv = (c == 0) ? t.x : (c == 1) ? t.y : (c == 2) ? t.z : t.w;
                float ov = (c == 0) ? o[u].x : (c == 1) ? o[u].y : (c == 2) ? o[u].z : o[u].w;
                float k = rintf((tv - p0) * inv_h);
                k = fminf(fmaxf(k, 0.0f), kmax);        // clamp to [0, P-1]
                float f = (k + 1.0f) * inv_maxbin;      // factors = (idx+1)/P
                float e = tv - ov;                      // targets - outputs
                acc += fmaxf((f - 1.0f) * e, f * e);    // pinball loss
            }
        }
    } else {
        // Generic fallback: R0-style grid-stride float4 loop.
        for (int i = blockIdx.x * THREADS + tid; i < n4; i += S) {
            float4 o = o4[i];
            float4 t = t4[i];
            #pragma unroll
            for (int c = 0; c < 4; ++c) {
                float tv = (c == 0) ? t.x : (c == 1) ? t.y : (c == 2) ? t.z : t.w;
                float ov = (c == 0) ? o.x : (c == 1) ? o.y : (c == 2) ? o.z : o.w;
                float k = rintf((tv - p0) * inv_h);
                k = fminf(fmaxf(k, 0.0f), kmax);
                float f = (k + 1.0f) * inv_maxbin;
                float e = tv - ov;
                acc += fmaxf((f - 1.0f) * e, f * e);
            }
        }
        // Scalar tail (n % 4 != 0).
        const int tail = n & 3;
        if (tail && blockIdx.x == 0 && tid < tail) {
            int j = (n4 << 2) + tid;
            float tv = targets[j];
            float ov = outputs[j];
            float k = rintf((tv - p0) * inv_h);
            k = fminf(fmaxf(k, 0.0f), kmax);
            float f = (k + 1.0f) * inv_maxbin;
            float e = tv - ov;
            acc += fmaxf((f - 1.0f) * e, f * e);
        }
    }

    // Wave (64-lane) shuffle reduction.
    #pragma unroll
    for (int off = 32; off > 0; off >>= 1)
        acc += __shfl_down(acc, off, 64);

    __shared__ float lds[THREADS / 64];
    const int lane = threadIdx.x & 63;
    const int wave = threadIdx.x >> 6;
    if (lane == 0) lds[wave] = acc;
    __syncthreads();
    if (threadIdx.x == 0) {
        float s = 0.0f;
        #pragma unroll
        for (int w = 0; w < THREADS / 64; ++w) s += lds[w];
        partials[blockIdx.x] = s;
    }
}

// Kernel 2: reduce block partials in double, write mean as f32.
__global__ __launch_bounds__(THREADS) void finalize_kernel(
    const float* __restrict__ partials, int nblocks,
    float* __restrict__ out, double inv_n) {

    double acc = 0.0;
    for (int i = threadIdx.x; i < nblocks; i += blockDim.x)
        acc += (double)partials[i];

    #pragma unroll
    for (int off = 32; off > 0; off >>= 1)
        acc += __shfl_down(acc, off, 64);

    __shared__ double lds[THREADS / 64];
    const int lane = threadIdx.x & 63;
    const int wave = threadIdx.x >> 6;
    if (lane == 0) lds[wave] = acc;
    __syncthreads();
    if (threadIdx.x == 0) {
        double s = 0.0;
        #pragma unroll
        for (int w = 0; w < THREADS / 64; ++w) s += lds[w];
        out[0] = (float)(s * inv_n);
    }
}

extern "C" void kernel_launch(void* const* d_in, const int* in_sizes, int n_in,
                              void* d_out, int out_size, void* d_ws, size_t ws_size,
                              hipStream_t stream) {
    const float* outputs     = (const float*)d_in[0];
    const float* targets     = (const float*)d_in[1];
    const float* percentiles = (const float*)d_in[2];
    float* out = (float*)d_out;

    const int n = in_sizes[0];
    const int P = in_sizes[2];

    float* partials = (float*)d_ws;   // GRID floats, fully written before read

    loss_partial_kernel<<<GRID, THREADS, 0, stream>>>(
        outputs, targets, percentiles, partials, n, P, 1.0f / (float)P);

    finalize_kernel<<<1, THREADS, 0, stream>>>(
        partials, GRID, out, 1.0 / (double)n);
}

// Round 5
// 146.300 us; speedup vs baseline: 2.2374x; 1.0465x over previous
//
#include <hip/hip_runtime.h>

#define THREADS 256
#define GRID 2048

// Kernel 1: per-block partial sums of the risk-aware MAE loss.
// percentiles is a uniform grid (linspace), so nearest-bin is analytic:
//   idx = clamp(rint((t - p0) * (P-1)/(pL - p0)), 0, P-1)
//
// SESSION CONCLUSION (R0-R4): this simple grid-stride float4 body is the
// fastest measured configuration (42.4-47 us). The kernel is pinned at the
// per-direction fabric read ceiling (~3.15 TB/s device-wide, = m13's 6.29
// TB/s copy counted per direction). Probes that did NOT move it: per-lane
// ILP 4/8 (R1/R3), LDS-DMA dual path (R4). Probe that regressed: fused
// atomic-tail finalize (R2, +185 us from 2048 serialized device-scope RMWs
// on one line at kernel tail). Do not re-try those.
__global__ __launch_bounds__(THREADS) void loss_partial_kernel(
    const float* __restrict__ outputs,
    const float* __restrict__ targets,
    const float* __restrict__ per,
    float* __restrict__ partials,
    int n, int P, float inv_maxbin) {

    // Uniform-grid parameters — wave-uniform scalar loads, L2-cached.
    const float p0 = per[0];
    const float pL = per[P - 1];
    const float inv_h = (float)(P - 1) / (pL - p0);
    const float kmax = (float)(P - 1);

    const int n4 = n >> 2;
    const float4* __restrict__ o4 = (const float4*)outputs;
    const float4* __restrict__ t4 = (const float4*)targets;

    float acc = 0.0f;

    const int stride = gridDim.x * blockDim.x;
    for (int i = blockIdx.x * blockDim.x + threadIdx.x; i < n4; i += stride) {
        float4 o = o4[i];
        float4 t = t4[i];

        #pragma unroll
        for (int c = 0; c < 4; ++c) {
            float tv = (c == 0) ? t.x : (c == 1) ? t.y : (c == 2) ? t.z : t.w;
            float ov = (c == 0) ? o.x : (c == 1) ? o.y : (c == 2) ? o.z : o.w;
            float k = rintf((tv - p0) * inv_h);
            k = fminf(fmaxf(k, 0.0f), kmax);        // clamp to [0, P-1]
            float f = (k + 1.0f) * inv_maxbin;      // factors = (idx+1)/P
            float e = tv - ov;                      // targets - outputs
            acc += fmaxf((f - 1.0f) * e, f * e);    // pinball loss
        }
    }

    // Scalar tail (n % 4 != 0) — no-op for N = 16M, kept for safety.
    const int tail = n & 3;
    if (tail && blockIdx.x == 0 && threadIdx.x < tail) {
        int i = (n4 << 2) + threadIdx.x;
        float tv = targets[i];
        float ov = outputs[i];
        float k = rintf((tv - p0) * inv_h);
        k = fminf(fmaxf(k, 0.0f), kmax);
        float f = (k + 1.0f) * inv_maxbin;
        float e = tv - ov;
        acc += fmaxf((f - 1.0f) * e, f * e);
    }

    // Wave (64-lane) shuffle reduction.
    #pragma unroll
    for (int off = 32; off > 0; off >>= 1)
        acc += __shfl_down(acc, off, 64);

    __shared__ float lds[THREADS / 64];
    const int lane = threadIdx.x & 63;
    const int wave = threadIdx.x >> 6;
    if (lane == 0) lds[wave] = acc;
    __syncthreads();
    if (threadIdx.x == 0) {
        float s = 0.0f;
        #pragma unroll
        for (int w = 0; w < THREADS / 64; ++w) s += lds[w];
        partials[blockIdx.x] = s;
    }
}

// Kernel 2: reduce block partials in double, write mean as f32.
__global__ __launch_bounds__(THREADS) void finalize_kernel(
    const float* __restrict__ partials, int nblocks,
    float* __restrict__ out, double inv_n) {

    double acc = 0.0;
    for (int i = threadIdx.x; i < nblocks; i += blockDim.x)
        acc += (double)partials[i];

    #pragma unroll
    for (int off = 32; off > 0; off >>= 1)
        acc += __shfl_down(acc, off, 64);

    __shared__ double lds[THREADS / 64];
    const int lane = threadIdx.x & 63;
    const int wave = threadIdx.x >> 6;
    if (lane == 0) lds[wave] = acc;
    __syncthreads();
    if (threadIdx.x == 0) {
        double s = 0.0;
        #pragma unroll
        for (int w = 0; w < THREADS / 64; ++w) s += lds[w];
        out[0] = (float)(s * inv_n);
    }
}

extern "C" void kernel_launch(void* const* d_in, const int* in_sizes, int n_in,
                              void* d_out, int out_size, void* d_ws, size_t ws_size,
                              hipStream_t stream) {
    const float* outputs     = (const float*)d_in[0];
    const float* targets     = (const float*)d_in[1];
    const float* percentiles = (const float*)d_in[2];
    float* out = (float*)d_out;

    const int n = in_sizes[0];
    const int P = in_sizes[2];

    float* partials = (float*)d_ws;   // GRID floats, fully written before read

    loss_partial_kernel<<<GRID, THREADS, 0, stream>>>(
        outputs, targets, percentiles, partials, n, P, 1.0f / (float)P);

    finalize_kernel<<<1, THREADS, 0, stream>>>(
        partials, GRID, out, 1.0 / (double)n);
}